// Round 10
// baseline (505.996 us; speedup 1.0000x reference)
//
#include <hip/hip_runtime.h>

#define B_ 32
#define Q_ 128
#define S_ 2048
#define C_ 1024
#define D_ 1024

typedef __attribute__((ext_vector_type(8))) short bf16x8;
typedef __attribute__((ext_vector_type(4))) float f32x4;

static __device__ __forceinline__ unsigned short f2bf(float f) {
  unsigned int u = __float_as_uint(f);
  u = (u + 0x7FFFu + ((u >> 16) & 1u)) >> 16;
  return (unsigned short)u;
}
static __device__ __forceinline__ float bf2f(unsigned short h) {
  return __uint_as_float(((unsigned int)h) << 16);
}

// Stage 16 consecutive f32 into hi+lo bf16 LDS tiles [128][64] (XOR-16B swizzle).
static __device__ __forceinline__ void stage16(unsigned short* hi, unsigned short* lo,
                                               const float* s, int r, int sc) {
  float v[16];
#pragma unroll
  for (int j = 0; j < 4; ++j) {
    f32x4 t = *(const f32x4*)(s + j * 4);
    v[j * 4 + 0] = t[0]; v[j * 4 + 1] = t[1]; v[j * 4 + 2] = t[2]; v[j * 4 + 3] = t[3];
  }
  unsigned short h[16], l[16];
#pragma unroll
  for (int e = 0; e < 16; ++e) {
    h[e] = f2bf(v[e]);
    float rres = v[e] - bf2f(h[e]);
    l[e] = f2bf(rres);
  }
  bf16x8 vh0, vh1, vl0, vl1;
#pragma unroll
  for (int e = 0; e < 8; ++e) {
    vh0[e] = (short)h[e]; vh1[e] = (short)h[e + 8];
    vl0[e] = (short)l[e]; vl1[e] = (short)l[e + 8];
  }
  const int swz = (r & 7) << 4;
  char* hrow = (char*)hi + r * 128;
  char* lrow = (char*)lo + r * 128;
  *(bf16x8*)(hrow + (((sc * 2) + 0)  ^ swz)) = vh0;
  *(bf16x8*)(hrow + (((sc * 2) + 16) ^ swz)) = vh1;
  *(bf16x8*)(lrow + (((sc * 2) + 0)  ^ swz)) = vl0;
  *(bf16x8*)(lrow + (((sc * 2) + 16) ^ swz)) = vl1;
}

// Stage 16 consecutive f32 as bf16 hi only (for A = f32 attention).
static __device__ __forceinline__ void stage16h(unsigned short* hi,
                                                const float* s, int r, int sc) {
  float v[16];
#pragma unroll
  for (int j = 0; j < 4; ++j) {
    f32x4 t = *(const f32x4*)(s + j * 4);
    v[j * 4 + 0] = t[0]; v[j * 4 + 1] = t[1]; v[j * 4 + 2] = t[2]; v[j * 4 + 3] = t[3];
  }
  bf16x8 vh0, vh1;
#pragma unroll
  for (int e = 0; e < 8; ++e) {
    vh0[e] = (short)f2bf(v[e]);
    vh1[e] = (short)f2bf(v[e + 8]);
  }
  const int swz = (r & 7) << 4;
  char* hrow = (char*)hi + r * 128;
  *(bf16x8*)(hrow + (((sc * 2) + 0)  ^ swz)) = vh0;
  *(bf16x8*)(hrow + (((sc * 2) + 16) ^ swz)) = vh1;
}

// Stage a 128x64 bf16 tile by pure 16B copies (rows K-contiguous, stride bRstride).
static __device__ __forceinline__ void stage_copy(unsigned short* dst,
                                                  const unsigned short* base,
                                                  long rstride, int kt, int tid) {
  const int r = tid >> 1;
  const int sc = (tid & 1) << 5;  // 0 or 32 bf16 cols
  const int swz = (r & 7) << 4;
  const unsigned short* s = base + (long)r * rstride + kt + sc;
  char* row = (char*)dst + r * 128;
#pragma unroll
  for (int j = 0; j < 4; ++j)
    *(bf16x8*)(row + ((sc * 2 + j * 16) ^ swz)) = *(const bf16x8*)(s + j * 8);
}

// C[m,n] = sum_k A[m,k]*B[n,k].
// AM/BM: 0 = f32 split (hi+lo, adds extra MFMA pass), 1 = f32 convert hi-only,
//        2 = bf16 copy. Strides in elements of the source dtype.
template <int AM, int BM>
__global__ __launch_bounds__(256, 2)
void gemm_k(const void* __restrict__ Aip, const void* __restrict__ Bip,
            float* __restrict__ outp, int K,
            long aBatch, long bBatch, long outBatch,
            long aRstride, long bRstride, long outRstride, int remapQB) {
  extern __shared__ char smem[];
  unsigned short* sA_hi = (unsigned short*)smem;  // [128][64]
  unsigned short* ptr = sA_hi + 128 * 64;
  unsigned short* sA_lo = nullptr;
  if constexpr (AM == 0) { sA_lo = ptr; ptr += 128 * 64; }
  unsigned short* sB_hi = ptr; ptr += 128 * 64;
  unsigned short* sB_lo = nullptr;
  if constexpr (BM == 0) { sB_lo = ptr; }

  const int tid = threadIdx.x;
  const int lane = tid & 63;
  const int wid = tid >> 6;
  const int wr = wid >> 1;
  const int wc = wid & 1;
  const int m0 = blockIdx.y * 128;
  const int n0 = blockIdx.x * 128;
  const int bz = blockIdx.z;
  const int frow = lane & 15;

  f32x4 acc[4][4];
#pragma unroll
  for (int i = 0; i < 4; ++i)
#pragma unroll
    for (int j = 0; j < 4; ++j) acc[i][j] = (f32x4){0.f, 0.f, 0.f, 0.f};

  for (int kt = 0; kt < K; kt += 64) {
    // ---- stage A ----
    if constexpr (AM == 0) {
      const float* Af = (const float*)Aip + (long)bz * aBatch;
      const int sr = tid >> 2;
      const int sc = (tid & 3) << 4;
#pragma unroll
      for (int p = 0; p < 2; ++p) {
        const int r = sr + (p << 6);
        stage16(sA_hi, sA_lo, Af + (long)(m0 + r) * aRstride + kt + sc, r, sc);
      }
    } else if constexpr (AM == 1) {
      const float* Af = (const float*)Aip + (long)bz * aBatch;
      const int sr = tid >> 2;
      const int sc = (tid & 3) << 4;
#pragma unroll
      for (int p = 0; p < 2; ++p) {
        const int r = sr + (p << 6);
        stage16h(sA_hi, Af + (long)(m0 + r) * aRstride + kt + sc, r, sc);
      }
    } else {
      const unsigned short* Ab = (const unsigned short*)Aip + (long)bz * aBatch;
      stage_copy(sA_hi, Ab + (long)m0 * aRstride, aRstride, kt, tid);
    }
    // ---- stage B ----
    if constexpr (BM == 0) {
      const float* Bf = (const float*)Bip + (long)bz * bBatch;
      const int sr = tid >> 2;
      const int sc = (tid & 3) << 4;
#pragma unroll
      for (int p = 0; p < 2; ++p) {
        const int r = sr + (p << 6);
        stage16(sB_hi, sB_lo, Bf + (long)(n0 + r) * bRstride + kt + sc, r, sc);
      }
    } else {
      const unsigned short* Bb = (const unsigned short*)Bip + (long)bz * bBatch;
      stage_copy(sB_hi, Bb + (long)n0 * bRstride, bRstride, kt, tid);
    }
    __syncthreads();

#pragma unroll
    for (int kk = 0; kk < 2; ++kk) {
      const int kb = kk * 64 + ((lane >> 4) << 4);
      bf16x8 ah[4], bh[4], al[4], bl[4];
#pragma unroll
      for (int i = 0; i < 4; ++i) {
        const int row = wr * 64 + i * 16 + frow;
        const int off = row * 128 + (kb ^ ((row & 7) << 4));
        ah[i] = *(const bf16x8*)((const char*)sA_hi + off);
        if constexpr (AM == 0) al[i] = *(const bf16x8*)((const char*)sA_lo + off);
      }
#pragma unroll
      for (int j = 0; j < 4; ++j) {
        const int row = wc * 64 + j * 16 + frow;
        const int off = row * 128 + (kb ^ ((row & 7) << 4));
        bh[j] = *(const bf16x8*)((const char*)sB_hi + off);
        if constexpr (BM == 0) bl[j] = *(const bf16x8*)((const char*)sB_lo + off);
      }
#pragma unroll
      for (int i = 0; i < 4; ++i)
#pragma unroll
        for (int j = 0; j < 4; ++j) {
          acc[i][j] = __builtin_amdgcn_mfma_f32_16x16x32_bf16(ah[i], bh[j], acc[i][j], 0, 0, 0);
          if constexpr (BM == 0)
            acc[i][j] = __builtin_amdgcn_mfma_f32_16x16x32_bf16(ah[i], bl[j], acc[i][j], 0, 0, 0);
          if constexpr (AM == 0)
            acc[i][j] = __builtin_amdgcn_mfma_f32_16x16x32_bf16(al[i], bh[j], acc[i][j], 0, 0, 0);
        }
    }
    __syncthreads();
  }

  float* out = outp + (long)bz * outBatch;
#pragma unroll
  for (int i = 0; i < 4; ++i) {
#pragma unroll
    for (int rr = 0; rr < 4; ++rr) {
      const int grow = m0 + wr * 64 + i * 16 + ((lane >> 4) << 2) + rr;
      const long orow = remapQB ? ((long)(grow & 31) * 128 + (grow >> 5)) : (long)grow;
      float* orp = out + orow * outRstride;
#pragma unroll
      for (int j = 0; j < 4; ++j) {
        const int col = n0 + wc * 64 + j * 16 + (lane & 15);
        orp[col] = acc[i][j][rr];
      }
    }
  }
}

// ctx [B][S][C] f32  ->  ctxT [B][C][S] bf16
__global__ __launch_bounds__(256)
void transpose_ctx(const float* __restrict__ ctx, unsigned short* __restrict__ ctxT) {
  __shared__ float tile[32][33];
  const int b = blockIdx.z;
  const int c0 = blockIdx.x * 32;
  const int s0 = blockIdx.y * 32;
  const int tx = threadIdx.x, ty = threadIdx.y;  // (32, 8)
  const float* src = ctx + ((long)b * S_ + s0) * C_ + c0;
#pragma unroll
  for (int i = ty; i < 32; i += 8) tile[i][tx] = src[(long)i * C_ + tx];
  __syncthreads();
  unsigned short* dst = ctxT + ((long)b * C_ + c0) * S_ + s0;
#pragma unroll
  for (int i = ty; i < 32; i += 8) dst[(long)i * S_ + tx] = f2bf(tile[tx][i]);
}

// ---------------------------------------------------------------------------
// Scan: 512 threads/block, 4 cols/thread. Round-9 asm pipeline (proven), with
// the bf16 side-write REMOVED: 2 VMEM ops/row (1 load + 1 store).
// vmcnt ladder: row0 wait 1 (younger: L1), row1 wait 2 (younger: S0, L2),
// rows>=2 wait 3 (younger: S(q-2), L(q+1), S(q-1)). Prefetch row clamped at
// Q-1 keeps per-row op count constant. One raw s_barrier per row; parity
// double-buffered LDS (m,s) slots; exact wave max; plain fmax/add butterflies;
// rcp on tot >= 1 (finite, safe).
// ---------------------------------------------------------------------------
template <int VM>
static __device__ __forceinline__ void scan_row(
    float* __restrict__ attn,
    int b, int q, int lane, int wid, int s0,
    const bool* msk, float* acc, f32x4& buf, float2 (&red)[2][8]) {
  const float L2E = 1.4426950408889634f;

  if constexpr (VM == 1)      asm volatile("s_waitcnt vmcnt(1)" ::: "memory");
  else if constexpr (VM == 2) asm volatile("s_waitcnt vmcnt(2)" ::: "memory");
  else                        asm volatile("s_waitcnt vmcnt(3)" ::: "memory");
  __builtin_amdgcn_sched_barrier(0);

  float adj[4];
#pragma unroll
  for (int j = 0; j < 4; ++j)
    adj[j] = msk[j] ? -1e30f : (buf[j] - acc[j]);

  // prefetch row q+2 into buf (dummy operands order adj-compute before reload)
  int pr = q + 2; if (pr > Q_ - 1) pr = Q_ - 1;
  const float* pp = attn + ((long)(pr * B_ + b)) * S_ + s0;
  asm volatile("global_load_dwordx4 %0, %1, off"
               : "=&v"(buf)
               : "v"(pp), "v"(adj[0]), "v"(adj[1]), "v"(adj[2]), "v"(adj[3])
               : "memory");

  float lm = fmaxf(fmaxf(adj[0], adj[1]), fmaxf(adj[2], adj[3]));
#pragma unroll
  for (int off = 32; off > 0; off >>= 1) lm = fmaxf(lm, __shfl_xor(lm, off));

  float e[4];
#pragma unroll
  for (int j = 0; j < 4; ++j) {
    const float x = exp2f((adj[j] - lm) * L2E);
    e[j] = msk[j] ? 0.f : x;
  }

  float ls = (e[0] + e[1]) + (e[2] + e[3]);
#pragma unroll
  for (int off = 32; off > 0; off >>= 1) ls += __shfl_xor(ls, off);

  const int p = q & 1;
  if (lane == 0) red[p][wid] = make_float2(lm, ls);
  asm volatile("s_waitcnt lgkmcnt(0)\n\ts_barrier" ::: "memory");

  const float2 v0 = red[p][0], v1 = red[p][1], v2 = red[p][2], v3 = red[p][3];
  const float2 v4 = red[p][4], v5 = red[p][5], v6 = red[p][6], v7 = red[p][7];
  const float M = fmaxf(fmaxf(fmaxf(v0.x, v1.x), fmaxf(v2.x, v3.x)),
                        fmaxf(fmaxf(v4.x, v5.x), fmaxf(v6.x, v7.x)));
  const float tot = v0.y * exp2f((v0.x - M) * L2E) + v1.y * exp2f((v1.x - M) * L2E) +
                    v2.y * exp2f((v2.x - M) * L2E) + v3.y * exp2f((v3.x - M) * L2E) +
                    v4.y * exp2f((v4.x - M) * L2E) + v5.y * exp2f((v5.x - M) * L2E) +
                    v6.y * exp2f((v6.x - M) * L2E) + v7.y * exp2f((v7.x - M) * L2E);
  // tot >= 1 (global argmax wave has s >= 1, m == M) -> rcp is finite & safe
  const float scale = exp2f((lm - M) * L2E) * __builtin_amdgcn_rcpf(tot);

  f32x4 av;
#pragma unroll
  for (int j = 0; j < 4; ++j) {
    av[j] = e[j] * scale;
    acc[j] += av[j];
  }
  *(f32x4*)(attn + ((long)(q * B_ + b)) * S_ + s0) = av;
}

__global__ __launch_bounds__(512)
void scan_kernel(const int* __restrict__ mask, float* __restrict__ attn,
                 float* __restrict__ accum_out) {
  const int b = blockIdx.x;
  const int tid = threadIdx.x;   // 0..511
  const int lane = tid & 63;
  const int wid = tid >> 6;      // 0..7
  const int s0 = tid * 4;

  __shared__ float2 red[2][8];

  // mask first; pin before the asm prefetches so its waitcnt precedes them
  const int4 mk = *(const int4*)(mask + (long)b * S_ + s0);
  const bool msk[4] = {mk.x != 0, mk.y != 0, mk.z != 0, mk.w != 0};
  asm volatile("" :: "v"(mk.x), "v"(mk.y), "v"(mk.z), "v"(mk.w));

  float acc[4] = {0.f, 0.f, 0.f, 0.f};

  f32x4 bufE, bufO;
  const float* p0 = attn + (long)b * S_ + s0;          // row 0
  asm volatile("global_load_dwordx4 %0, %1, off" : "=&v"(bufE) : "v"(p0) : "memory");
  const float* p1 = attn + ((long)(B_ + b)) * S_ + s0; // row 1
  asm volatile("global_load_dwordx4 %0, %1, off" : "=&v"(bufO) : "v"(p1) : "memory");

  scan_row<1>(attn, b, 0, lane, wid, s0, msk, acc, bufE, red);
  scan_row<2>(attn, b, 1, lane, wid, s0, msk, acc, bufO, red);
  for (int q = 2; q < Q_; q += 2) {
    scan_row<3>(attn, b, q,     lane, wid, s0, msk, acc, bufE, red);
    scan_row<3>(attn, b, q + 1, lane, wid, s0, msk, acc, bufO, red);
  }

  f32x4 a4;
#pragma unroll
  for (int j = 0; j < 4; ++j) a4[j] = acc[j];
  *(f32x4*)(accum_out + (long)b * S_ + s0) = a4;
}

extern "C" void kernel_launch(void* const* d_in, const int* in_sizes, int n_in,
                              void* d_out, int out_size, void* d_ws, size_t ws_size,
                              hipStream_t stream) {
  const float* ctx   = (const float*)d_in[0];  // [B,S,C] f32
  const float* query = (const float*)d_in[1];  // [Q,B,D] f32
  const int*   mask  = (const int*)d_in[2];    // [B,S] int32 (bool)
  const float* W     = (const float*)d_in[3];  // [C,D] f32

  float* out = (float*)d_out;
  float* attn = out;                                      // [Q,B,S]
  float* accum_out = out + (size_t)Q_ * B_ * S_;          // [B,1,S]
  float* comp = accum_out + (size_t)B_ * S_;              // [Q,B,C]

  char* ws = (char*)d_ws;
  float* qw = (float*)ws;                                                   // [B,Q,C] f32, 16 MiB
  unsigned short* ctxT = (unsigned short*)(ws + (size_t)16 * 1024 * 1024);  // [B,C,S] bf16, 128 MiB

  // 1) ctx -> ctxT (bf16, transposed) for the composition GEMM
  transpose_ctx<<<dim3(C_ / 32, S_ / 32, B_), dim3(32, 8), 0, stream>>>(ctx, ctxT);

  // 2) QW[b,q,c] = sum_d query[q,b,d] * W[c,d]   (3-pass split for precision)
  gemm_k<0, 0><<<dim3(C_ / 128, (Q_ * B_) / 128, 1), 256, 65536, stream>>>(
      query, W, qw, D_, 0L, 0L, 0L, (long)D_, (long)D_, (long)C_, 1);

  // 3) scores[q,b,s] = sum_c QW[b,q,c] * ctx[b,s,c]  -> attention region of d_out
  gemm_k<0, 0><<<dim3(S_ / 128, 1, B_), 256, 65536, stream>>>(
      qw, ctx, attn, C_, (long)Q_ * C_, (long)S_ * C_, (long)S_,
      (long)C_, (long)C_, (long)B_ * S_, 0);

  // 4) sequential coverage-softmax scan (in-place attention + accum)
  scan_kernel<<<B_, 512, 0, stream>>>(mask, attn, accum_out);

  // 5) composition[q,b,c] = sum_s attn[q,b,s] * ctx[b,s,c]
  //    A = f32 attention [q][b][s]: per-b offset = b*S, row stride = B*S.
  gemm_k<1, 2><<<dim3(C_ / 128, 1, B_), 256, 32768, stream>>>(
      attn, ctxT, comp, S_, (long)S_, (long)C_ * S_, (long)C_,
      (long)B_ * S_, (long)S_, (long)B_ * C_, 0);
}

// Round 11
// 412.217 us; speedup vs baseline: 1.2275x; 1.2275x over previous
//
#include <hip/hip_runtime.h>

#define B_ 32
#define Q_ 128
#define S_ 2048
#define C_ 1024
#define D_ 1024

typedef __attribute__((ext_vector_type(8))) short bf16x8;
typedef __attribute__((ext_vector_type(4))) float f32x4;

static __device__ __forceinline__ unsigned short f2bf(float f) {
  unsigned int u = __float_as_uint(f);
  u = (u + 0x7FFFu + ((u >> 16) & 1u)) >> 16;
  return (unsigned short)u;
}
static __device__ __forceinline__ float bf2f(unsigned short h) {
  return __uint_as_float(((unsigned int)h) << 16);
}

// Stage 16 consecutive f32 into hi+lo bf16 LDS tiles [128][64] (XOR-16B swizzle).
static __device__ __forceinline__ void stage16(unsigned short* hi, unsigned short* lo,
                                               const float* s, int r, int sc) {
  float v[16];
#pragma unroll
  for (int j = 0; j < 4; ++j) {
    f32x4 t = *(const f32x4*)(s + j * 4);
    v[j * 4 + 0] = t[0]; v[j * 4 + 1] = t[1]; v[j * 4 + 2] = t[2]; v[j * 4 + 3] = t[3];
  }
  unsigned short h[16], l[16];
#pragma unroll
  for (int e = 0; e < 16; ++e) {
    h[e] = f2bf(v[e]);
    float rres = v[e] - bf2f(h[e]);
    l[e] = f2bf(rres);
  }
  bf16x8 vh0, vh1, vl0, vl1;
#pragma unroll
  for (int e = 0; e < 8; ++e) {
    vh0[e] = (short)h[e]; vh1[e] = (short)h[e + 8];
    vl0[e] = (short)l[e]; vl1[e] = (short)l[e + 8];
  }
  const int swz = (r & 7) << 4;
  char* hrow = (char*)hi + r * 128;
  char* lrow = (char*)lo + r * 128;
  *(bf16x8*)(hrow + (((sc * 2) + 0)  ^ swz)) = vh0;
  *(bf16x8*)(hrow + (((sc * 2) + 16) ^ swz)) = vh1;
  *(bf16x8*)(lrow + (((sc * 2) + 0)  ^ swz)) = vl0;
  *(bf16x8*)(lrow + (((sc * 2) + 16) ^ swz)) = vl1;
}

// Stage a 128x64 bf16 tile by pure 16B copies (rows K-contiguous).
static __device__ __forceinline__ void stage_copy(unsigned short* dst,
                                                  const unsigned short* base,
                                                  long rstride, int kt, int tid) {
  const int r = tid >> 1;
  const int sc = (tid & 1) << 5;  // 0 or 32 bf16 cols
  const int swz = (r & 7) << 4;
  const unsigned short* s = base + (long)r * rstride + kt + sc;
  char* row = (char*)dst + r * 128;
#pragma unroll
  for (int j = 0; j < 4; ++j)
    *(bf16x8*)(row + ((sc * 2 + j * 16) ^ swz)) = *(const bf16x8*)(s + j * 8);
}

// C[m,n] = sum_k A[m,k]*B[n,k].
// AM/BM: 0 = f32 split (hi+lo, 3-pass MFMA), 2 = bf16 copy (1-pass).
// FUSE: write the staged B hi-tile (bf16 of B) transposed to fuseOut
//       [bz][k][n] — used by the scores GEMM to produce ctxT for free.
template <int AM, int BM, bool FUSE>
__global__ __launch_bounds__(256, 2)
void gemm_k(const void* __restrict__ Aip, const void* __restrict__ Bip,
            float* __restrict__ outp, int K,
            long aBatch, long bBatch, long outBatch,
            long aRstride, long bRstride, long outRstride, int remapQB,
            unsigned short* __restrict__ fuseOut, long fuseRstride) {
  extern __shared__ char smem[];
  unsigned short* sA_hi = (unsigned short*)smem;  // [128][64]
  unsigned short* ptr = sA_hi + 128 * 64;
  unsigned short* sA_lo = nullptr;
  if constexpr (AM == 0) { sA_lo = ptr; ptr += 128 * 64; }
  unsigned short* sB_hi = ptr; ptr += 128 * 64;
  unsigned short* sB_lo = nullptr;
  if constexpr (BM == 0) { sB_lo = ptr; }

  const int tid = threadIdx.x;
  const int lane = tid & 63;
  const int wid = tid >> 6;
  const int wr = wid >> 1;
  const int wc = wid & 1;
  const int m0 = blockIdx.y * 128;
  const int n0 = blockIdx.x * 128;
  const int bz = blockIdx.z;
  const int frow = lane & 15;

  f32x4 acc[4][4];
#pragma unroll
  for (int i = 0; i < 4; ++i)
#pragma unroll
    for (int j = 0; j < 4; ++j) acc[i][j] = (f32x4){0.f, 0.f, 0.f, 0.f};

  for (int kt = 0; kt < K; kt += 64) {
    // ---- stage A ----
    if constexpr (AM == 0) {
      const float* Af = (const float*)Aip + (long)bz * aBatch;
      const int sr = tid >> 2;
      const int sc = (tid & 3) << 4;
#pragma unroll
      for (int p = 0; p < 2; ++p) {
        const int r = sr + (p << 6);
        stage16(sA_hi, sA_lo, Af + (long)(m0 + r) * aRstride + kt + sc, r, sc);
      }
    } else {
      const unsigned short* Ab = (const unsigned short*)Aip + (long)bz * aBatch;
      stage_copy(sA_hi, Ab + (long)m0 * aRstride, aRstride, kt, tid);
    }
    // ---- stage B ----
    if constexpr (BM == 0) {
      const float* Bf = (const float*)Bip + (long)bz * bBatch;
      const int sr = tid >> 2;
      const int sc = (tid & 3) << 4;
#pragma unroll
      for (int p = 0; p < 2; ++p) {
        const int r = sr + (p << 6);
        stage16(sB_hi, sB_lo, Bf + (long)(n0 + r) * bRstride + kt + sc, r, sc);
      }
    } else {
      const unsigned short* Bb = (const unsigned short*)Bip + (long)bz * bBatch;
      stage_copy(sB_hi, Bb + (long)n0 * bRstride, bRstride, kt, tid);
    }
    __syncthreads();

#pragma unroll
    for (int kk = 0; kk < 2; ++kk) {
      const int kb = kk * 64 + ((lane >> 4) << 4);
      bf16x8 ah[4], bh[4], al[4], bl[4];
#pragma unroll
      for (int i = 0; i < 4; ++i) {
        const int row = wr * 64 + i * 16 + frow;
        const int off = row * 128 + (kb ^ ((row & 7) << 4));
        ah[i] = *(const bf16x8*)((const char*)sA_hi + off);
        if constexpr (AM == 0) al[i] = *(const bf16x8*)((const char*)sA_lo + off);
      }
#pragma unroll
      for (int j = 0; j < 4; ++j) {
        const int row = wc * 64 + j * 16 + frow;
        const int off = row * 128 + (kb ^ ((row & 7) << 4));
        bh[j] = *(const bf16x8*)((const char*)sB_hi + off);
        if constexpr (BM == 0) bl[j] = *(const bf16x8*)((const char*)sB_lo + off);
      }
#pragma unroll
      for (int i = 0; i < 4; ++i)
#pragma unroll
        for (int j = 0; j < 4; ++j) {
          acc[i][j] = __builtin_amdgcn_mfma_f32_16x16x32_bf16(ah[i], bh[j], acc[i][j], 0, 0, 0);
          if constexpr (BM == 0)
            acc[i][j] = __builtin_amdgcn_mfma_f32_16x16x32_bf16(ah[i], bl[j], acc[i][j], 0, 0, 0);
          if constexpr (AM == 0)
            acc[i][j] = __builtin_amdgcn_mfma_f32_16x16x32_bf16(al[i], bh[j], acc[i][j], 0, 0, 0);
        }
    }

    // ---- fused transposed write-out of the staged B hi-tile ----
    // sB_hi holds bf16(B rows n0..n0+127, k-cols kt..kt+63). Write
    // fuseOut[bz][kt+lane][n0 + wid*32 .. +31] (64B contiguous per lane).
    // Element (row, c) byte in LDS: row*128 + (((c>>3)^(row&7))<<4) + (c&7)*2.
    if constexpr (FUSE) {
      unsigned short vals[32];
#pragma unroll
      for (int i = 0; i < 32; ++i) {
        const int row = wid * 32 + i;
        vals[i] = *(const unsigned short*)((const char*)sB_hi + row * 128 +
                   ((((lane >> 3) ^ (row & 7)) << 4) + ((lane & 7) << 1)));
      }
      unsigned short* dst = fuseOut + ((long)bz * K + kt + lane) * fuseRstride +
                            n0 + wid * 32;
#pragma unroll
      for (int j = 0; j < 4; ++j)
        *(bf16x8*)(dst + j * 8) = *(const bf16x8*)(vals + j * 8);
    }
    __syncthreads();
  }

  float* out = outp + (long)bz * outBatch;
#pragma unroll
  for (int i = 0; i < 4; ++i) {
#pragma unroll
    for (int rr = 0; rr < 4; ++rr) {
      const int grow = m0 + wr * 64 + i * 16 + ((lane >> 4) << 2) + rr;
      const long orow = remapQB ? ((long)(grow & 31) * 128 + (grow >> 5)) : (long)grow;
      float* orp = out + orow * outRstride;
#pragma unroll
      for (int j = 0; j < 4; ++j) {
        const int col = n0 + wc * 64 + j * 16 + (lane & 15);
        orp[col] = acc[i][j][rr];
      }
    }
  }
}

// ---------------------------------------------------------------------------
// Scan (round-9 proven, verbatim): 512 threads/block, 4 cols/thread.
// asm global_load_dwordx4 prefetch depth 2 + counted vmcnt; 3 VMEM ops/row
// (1 load + 2 stores) -> ladder 1/3/5; one raw s_barrier per row; parity
// double-buffered LDS (m,s); exact wave max; plain fmax/add butterflies.
// ---------------------------------------------------------------------------
template <int VM>
static __device__ __forceinline__ void scan_row(
    float* __restrict__ attn, unsigned short* __restrict__ attnb,
    int b, int q, int lane, int wid, int s0,
    const bool* msk, float* acc, f32x4& buf, float2 (&red)[2][8]) {
  const float L2E = 1.4426950408889634f;

  if constexpr (VM == 1)      asm volatile("s_waitcnt vmcnt(1)" ::: "memory");
  else if constexpr (VM == 3) asm volatile("s_waitcnt vmcnt(3)" ::: "memory");
  else                        asm volatile("s_waitcnt vmcnt(5)" ::: "memory");
  __builtin_amdgcn_sched_barrier(0);

  float adj[4];
#pragma unroll
  for (int j = 0; j < 4; ++j)
    adj[j] = msk[j] ? -1e30f : (buf[j] - acc[j]);

  int pr = q + 2; if (pr > Q_ - 1) pr = Q_ - 1;
  const float* pp = attn + ((long)(pr * B_ + b)) * S_ + s0;
  asm volatile("global_load_dwordx4 %0, %1, off"
               : "=&v"(buf)
               : "v"(pp), "v"(adj[0]), "v"(adj[1]), "v"(adj[2]), "v"(adj[3])
               : "memory");

  float lm = fmaxf(fmaxf(adj[0], adj[1]), fmaxf(adj[2], adj[3]));
#pragma unroll
  for (int off = 32; off > 0; off >>= 1) lm = fmaxf(lm, __shfl_xor(lm, off));

  float e[4];
#pragma unroll
  for (int j = 0; j < 4; ++j) {
    const float x = exp2f((adj[j] - lm) * L2E);
    e[j] = msk[j] ? 0.f : x;
  }

  float ls = (e[0] + e[1]) + (e[2] + e[3]);
#pragma unroll
  for (int off = 32; off > 0; off >>= 1) ls += __shfl_xor(ls, off);

  const int p = q & 1;
  if (lane == 0) red[p][wid] = make_float2(lm, ls);
  asm volatile("s_waitcnt lgkmcnt(0)\n\ts_barrier" ::: "memory");

  const float2 v0 = red[p][0], v1 = red[p][1], v2 = red[p][2], v3 = red[p][3];
  const float2 v4 = red[p][4], v5 = red[p][5], v6 = red[p][6], v7 = red[p][7];
  const float M = fmaxf(fmaxf(fmaxf(v0.x, v1.x), fmaxf(v2.x, v3.x)),
                        fmaxf(fmaxf(v4.x, v5.x), fmaxf(v6.x, v7.x)));
  const float tot = v0.y * exp2f((v0.x - M) * L2E) + v1.y * exp2f((v1.x - M) * L2E) +
                    v2.y * exp2f((v2.x - M) * L2E) + v3.y * exp2f((v3.x - M) * L2E) +
                    v4.y * exp2f((v4.x - M) * L2E) + v5.y * exp2f((v5.x - M) * L2E) +
                    v6.y * exp2f((v6.x - M) * L2E) + v7.y * exp2f((v7.x - M) * L2E);
  const float scale = exp2f((lm - M) * L2E) / tot;

  f32x4 av;
#pragma unroll
  for (int j = 0; j < 4; ++j) {
    av[j] = e[j] * scale;
    acc[j] += av[j];
  }
  *(f32x4*)(attn + ((long)(q * B_ + b)) * S_ + s0) = av;
  uint2 pk;
  pk.x = (unsigned int)f2bf(av[0]) | ((unsigned int)f2bf(av[1]) << 16);
  pk.y = (unsigned int)f2bf(av[2]) | ((unsigned int)f2bf(av[3]) << 16);
  *(uint2*)(attnb + ((long)b * Q_ + q) * S_ + s0) = pk;
}

__global__ __launch_bounds__(512)
void scan_kernel(const int* __restrict__ mask, float* __restrict__ attn,
                 float* __restrict__ accum_out, unsigned short* __restrict__ attnb) {
  const int b = blockIdx.x;
  const int tid = threadIdx.x;   // 0..511
  const int lane = tid & 63;
  const int wid = tid >> 6;      // 0..7
  const int s0 = tid * 4;

  __shared__ float2 red[2][8];

  const int4 mk = *(const int4*)(mask + (long)b * S_ + s0);
  const bool msk[4] = {mk.x != 0, mk.y != 0, mk.z != 0, mk.w != 0};
  asm volatile("" :: "v"(mk.x), "v"(mk.y), "v"(mk.z), "v"(mk.w));

  float acc[4] = {0.f, 0.f, 0.f, 0.f};

  f32x4 bufE, bufO;
  const float* p0 = attn + (long)b * S_ + s0;          // row 0
  asm volatile("global_load_dwordx4 %0, %1, off" : "=&v"(bufE) : "v"(p0) : "memory");
  const float* p1 = attn + ((long)(B_ + b)) * S_ + s0; // row 1
  asm volatile("global_load_dwordx4 %0, %1, off" : "=&v"(bufO) : "v"(p1) : "memory");

  scan_row<1>(attn, attnb, b, 0, lane, wid, s0, msk, acc, bufE, red);
  scan_row<3>(attn, attnb, b, 1, lane, wid, s0, msk, acc, bufO, red);
  for (int q = 2; q < Q_; q += 2) {
    scan_row<5>(attn, attnb, b, q,     lane, wid, s0, msk, acc, bufE, red);
    scan_row<5>(attn, attnb, b, q + 1, lane, wid, s0, msk, acc, bufO, red);
  }

  f32x4 a4;
#pragma unroll
  for (int j = 0; j < 4; ++j) a4[j] = acc[j];
  *(f32x4*)(accum_out + (long)b * S_ + s0) = a4;
}

extern "C" void kernel_launch(void* const* d_in, const int* in_sizes, int n_in,
                              void* d_out, int out_size, void* d_ws, size_t ws_size,
                              hipStream_t stream) {
  const float* ctx   = (const float*)d_in[0];  // [B,S,C] f32
  const float* query = (const float*)d_in[1];  // [Q,B,D] f32
  const int*   mask  = (const int*)d_in[2];    // [B,S] int32 (bool)
  const float* W     = (const float*)d_in[3];  // [C,D] f32

  float* out = (float*)d_out;
  float* attn = out;                                      // [Q,B,S]
  float* accum_out = out + (size_t)Q_ * B_ * S_;          // [B,1,S]
  float* comp = accum_out + (size_t)B_ * S_;              // [Q,B,C]

  char* ws = (char*)d_ws;
  float* qw = (float*)ws;                                                   // [B,Q,C] f32, 16 MiB
  unsigned short* ctxT  = (unsigned short*)(ws + (size_t)16 * 1024 * 1024); // [B,C,S] bf16, 128 MiB
  unsigned short* attnb = (unsigned short*)(ws + (size_t)16 * 1024 * 1024 +
                                            (size_t)B_ * C_ * S_ * 2);      // [B,Q,S] bf16, 16 MiB

  // 1) QW[b,q,c] = sum_d query[q,b,d] * W[c,d]   (3-pass split for precision)
  gemm_k<0, 0, false><<<dim3(C_ / 128, (Q_ * B_) / 128, 1), 256, 65536, stream>>>(
      query, W, qw, D_, 0L, 0L, 0L, (long)D_, (long)D_, (long)C_, 1, nullptr, 0L);

  // 2) scores[q,b,s] = sum_c QW[b,q,c] * ctx[b,s,c]  -> attention region of
  //    d_out, AND fused ctxT[b][c][s] write-out from the staged B tiles.
  gemm_k<0, 0, true><<<dim3(S_ / 128, 1, B_), 256, 65536, stream>>>(
      qw, ctx, attn, C_, (long)Q_ * C_, (long)S_ * C_, (long)S_,
      (long)C_, (long)C_, (long)B_ * S_, 0, ctxT, (long)S_);

  // 3) sequential coverage-softmax scan (in-place attention + accum + bf16 copy)
  scan_kernel<<<B_, 512, 0, stream>>>(mask, attn, accum_out, attnb);

  // 4) composition[q,b,c] = sum_s attnb[b,q,s] * ctxT[b,c,s]
  gemm_k<2, 2, false><<<dim3(C_ / 128, 1, B_), 256, 32768, stream>>>(
      attnb, ctxT, comp, S_, (long)Q_ * S_, (long)C_ * S_, (long)C_,
      (long)S_, (long)S_, (long)B_ * C_, 0, nullptr, 0L);
}